// Round 1
// baseline (15379.033 us; speedup 1.0000x reference)
//
#include <hip/hip_runtime.h>
#include <math.h>

// IDE state-space Kalman filter, MI355X (gfx950). Round 8:
// - K = I - r2*Sinv identity (H=I, R=r2 I): Phase Y deleted; Pn = M^T M
//   (= Sm^-1) directly; P_new = r2 I - r2^2 Sinv; merge mv += vv - r2*(Sinv v).
//   P' no longer packs predicted P to bf16 (dead) nor mirrors Wf upper (dead).
// - chol trailing lookahead: 4x4 register tiles, quad-per-pair, waves 1..15
//   (4x less LDS read traffic; full 16x16 tiles incl. diag-pair upper).
// - panel TRSM: 8 threads/row, 2 outputs each (wave-lockstep safe).
// - trinv phase 1: wave-per-pair 2x2 register tiles (2x less LDS traffic).
// - MC gather vectorized (float4 per 16-col block); Mb pack dropped.

#define SQ 64
#define DQ 128
#define TQ 128
#define BQ 16
#define LDP 132           // fp32 row stride
#define LDB 136           // bf16 row stride (16B-aligned rows, 2-way banks)
#define WFLOATS 17408     // W region: 69632 B (holds 2 bf16 matrices)
#define NTH 1024
#define LOG2PI 1.8378770664093454f

#define SMEM_FLOATS 37520

typedef __attribute__((ext_vector_type(8))) short bf16x8;
typedef __attribute__((ext_vector_type(4))) float f32x4;

#define DOT4(A, X, Y) \
  A = fmaf((X).x, (Y).x, fmaf((X).y, (Y).y, fmaf((X).z, (Y).z, fmaf((X).w, (Y).w, A))))

__device__ __forceinline__ unsigned short f2bf(float f) {
  unsigned u = __float_as_uint(f);
  u += 0x7fffu + ((u >> 16) & 1u);
  return (unsigned short)(u >> 16);
}
__device__ __forceinline__ float bf2f(unsigned short h) {
  return __uint_as_float(((unsigned)h) << 16);
}
__device__ __forceinline__ uint4 pack8(const float* v) {
  uint4 r;
  r.x = (unsigned)f2bf(v[0]) | ((unsigned)f2bf(v[1]) << 16);
  r.y = (unsigned)f2bf(v[2]) | ((unsigned)f2bf(v[3]) << 16);
  r.z = (unsigned)f2bf(v[4]) | ((unsigned)f2bf(v[5]) << 16);
  r.w = (unsigned)f2bf(v[6]) | ((unsigned)f2bf(v[7]) << 16);
  return r;
}

__device__ __forceinline__ float block_reduce_sum(float v, float* red) {
  #pragma unroll
  for (int off = 32; off > 0; off >>= 1) v += __shfl_down(v, off);
  const int tid = threadIdx.x;
  if ((tid & 63) == 0) red[tid >> 6] = v;
  __syncthreads();
  v = 0.0f;
  #pragma unroll
  for (int w = 0; w < NTH / 64; w++) v += red[w];
  __syncthreads();
  return v;
}

// 16x16 Cholesky + triangular inverse on wave 0 (register/shfl resident).
__device__ __forceinline__ void chol16(float* __restrict__ Wf,
                                       float* __restrict__ mdiag,
                                       int b0, int lane) {
  float a[16];
  if (lane < 16) {
    const float4* rp = (const float4*)(Wf + (b0 + lane) * LDP + b0);
    float4 q0 = rp[0], q1 = rp[1], q2v = rp[2], q3 = rp[3];
    a[0]=q0.x; a[1]=q0.y; a[2]=q0.z; a[3]=q0.w;
    a[4]=q1.x; a[5]=q1.y; a[6]=q1.z; a[7]=q1.w;
    a[8]=q2v.x; a[9]=q2v.y; a[10]=q2v.z; a[11]=q2v.w;
    a[12]=q3.x; a[13]=q3.y; a[14]=q3.z; a[15]=q3.w;
  } else {
    #pragma unroll
    for (int i = 0; i < 16; i++) a[i] = 1.0f;
  }
  float myrinv = 1.0f;
  #pragma unroll
  for (int j = 0; j < 16; j++) {
    float dj = __shfl(a[j], j);
    float rinv = rsqrtf(dj);
    float lij = a[j] * rinv;
    a[j] = lij;
    if (lane == j) myrinv = rinv;
    #pragma unroll
    for (int k = j + 1; k < 16; k++) {
      float lkj = __shfl(lij, k);
      a[k] = fmaf(-lij, lkj, a[k]);
    }
  }
  if (lane < 16) {
    float4* rp = (float4*)(Wf + (b0 + lane) * LDP + b0);
    rp[0] = make_float4(a[0], a[1], a[2], a[3]);
    rp[1] = make_float4(a[4], a[5], a[6], a[7]);
    rp[2] = make_float4(a[8], a[9], a[10], a[11]);
    rp[3] = make_float4(a[12], a[13], a[14], a[15]);
    mdiag[b0 + lane] = myrinv;
  }
  float x[16];
  #pragma unroll
  for (int i = 0; i < 16; i++) {
    float s = (i == lane) ? 1.0f : 0.0f;
    #pragma unroll
    for (int k = 0; k < 16; k++) {
      if (k < i) {
        float Lik = __shfl(a[k], i);
        s = fmaf(-Lik, x[k], s);
      }
    }
    float ri = __shfl(myrinv, i);
    x[i] = (i < lane) ? 0.0f : s * ri;
  }
  if (lane < 16) {
    #pragma unroll
    for (int i = 0; i < 16; i++)
      if (i > lane) Wf[(b0 + lane) * LDP + (b0 + i)] = x[i];
  }
}

extern "C" __global__ __launch_bounds__(NTH, 4)
void ide_kf_kernel(const float* __restrict__ z_seq,
                   const float* __restrict__ site_lon,
                   const float* __restrict__ site_lat,
                   const float* __restrict__ mu_seq,
                   const float* __restrict__ sigma_seq,
                   const float* __restrict__ log_q,
                   const float* __restrict__ log_r,
                   const float* __restrict__ log_p0,
                   const float* __restrict__ log_damp,
                   const float* __restrict__ init_mean,
                   const float* __restrict__ coupling_raw,
                   float* __restrict__ ws) {
  extern __shared__ float smem[];
  float* Wf     = smem;                  // 17408 floats (fp32 chol space)
  float* B1f    = Wf + WFLOATS;          // 8704 floats (Ab bf16)
  float* B2f    = B1f + 8704;            // 8704 floats (Pb bf16)
  float* gtmp   = B2f + 8704;            // 2048
  float* coords = gtmp + 2048;           // 128
  float* mv     = coords + 128;          // 128
  float* vv     = mv + DQ;               // 128
  float* yv     = vv + DQ;               // 128
  float* mdiag  = yv + DQ;               // 128
  float* red    = mdiag + DQ;            // 16

  unsigned short* Tb  = (unsigned short*)Wf;            // bf16, stride LDB
  unsigned short* Mtb = (unsigned short*)Wf;            // M^T row-major bf16
  unsigned short* Ab  = (unsigned short*)B1f;           // A bf16
  unsigned short* Pb  = (unsigned short*)B2f;           // P bf16 (symmetric)

  const int tid = threadIdx.x;
  const int lane = tid & 63;
  const int wave = tid >> 6;
  const int rb = wave >> 1, ch = wave & 1;
  const int m16 = lane & 15, quad = lane >> 4;
  const int b = blockIdx.x;
  float* nll_out = ws;

  const float r2 = __expf(2.0f * log_r[0]);
  const float q2 = __expf(2.0f * log_q[0]);
  const float p0sq = __expf(2.0f * log_p0[0]);
  const float damping = __expf(log_damp[0]);
  const float cpl00 = 1.0f + 0.25f * tanhf(coupling_raw[0]);
  const float cpl01 = 0.25f * tanhf(coupling_raw[1]);
  const float cpl10 = 0.25f * tanhf(coupling_raw[2]);
  const float cpl11 = 1.0f + 0.25f * tanhf(coupling_raw[3]);

  // chol-trailing lookahead assignment: quad-per-pair over waves 1..15.
  // pairs (bi,bj), bi>=1, bj<=bi; cnt = bi*(bi+1)/2 + bj - 1 == slot.
  int pbi = 64, pbj = 0;
  if (wave >= 1) {
    const int slot = (wave - 1) * 4 + quad;
    int bi = 1;
    while (bi * (bi + 1) / 2 + bi - 1 < slot) bi++;
    pbi = bi;
    pbj = slot + 1 - bi * (bi + 1) / 2;
  }

  // ---- lon/lat projection ----
  float myLon = (tid < SQ) ? site_lon[tid] : 0.0f;
  float myLat = (tid < SQ) ? site_lat[tid] : 0.0f;
  float lat0 = block_reduce_sum(myLat, red) * (1.0f / 64.0f);
  float lon0 = block_reduce_sum(myLon, red) * (1.0f / 64.0f);
  if (tid < SQ) {
    const float km = 111.32f;
    float cs = cosf(lat0 * 0.017453292519943295f);
    coords[2 * tid]     = (myLon - lon0) * (km * cs);
    coords[2 * tid + 1] = (myLat - lat0) * km;
  }
  __syncthreads();
  float dsum = 0.0f, dcnt = 0.0f;
  for (int idx = tid; idx < SQ * SQ; idx += NTH) {
    int i = idx >> 6, j = idx & 63;
    float dx = coords[2 * i] - coords[2 * j];
    float dy = coords[2 * i + 1] - coords[2 * j + 1];
    float d = sqrtf(dx * dx + dy * dy + 1e-12f);
    dsum += d;
    if (d > 1e-6f) dcnt += 1.0f;
  }
  dsum = block_reduce_sum(dsum, red);
  dcnt = block_reduce_sum(dcnt, red);
  float scale = dsum / fmaxf(dcnt, 1.0f);
  float sdiv = 1.0f / fmaxf(scale, 1e-6f);
  if (tid < SQ) { coords[2 * tid] *= sdiv; coords[2 * tid + 1] *= sdiv; }

  // ---- init: Pb = bf16(p0sq I), Wf = (p0sq+r2) I, mv = init_mean ----
  for (int e = tid; e < WFLOATS / 4; e += NTH)
    ((float4*)Wf)[e] = make_float4(0.0f, 0.0f, 0.0f, 0.0f);
  for (int e = tid; e < 8704 / 4; e += NTH)
    ((float4*)B2f)[e] = make_float4(0.0f, 0.0f, 0.0f, 0.0f);
  __syncthreads();
  if (tid < DQ) {
    Wf[tid * LDP + tid] = p0sq + r2;
    Pb[tid * LDB + tid] = f2bf(p0sq);
    mv[tid] = init_mean[tid];
  }
  __syncthreads();

  float nllp = 0.0f;

  #pragma unroll 1
  for (int t = 0; t < TQ; t++) {
    const float* zt = z_seq + ((size_t)b * TQ + t) * DQ;

    if (t > 0) {
      const float* mu_t = mu_seq + ((size_t)b * (TQ - 1) + (t - 1)) * 4;
      const float* sg_t = sigma_seq + ((size_t)b * (TQ - 1) + (t - 1)) * 16;

      // ---- PHASE A: merge m-update partials + build A -> Ab (bf16) ----
      // m_new = m' + v - r2 * (Sinv v); partials s hold (Sinv v) pieces.
      if (tid < DQ) {
        float s = gtmp[2 * tid] + gtmp[2 * tid + 1];
        #pragma unroll
        for (int rb8 = 0; rb8 < 8; rb8++) s += gtmp[256 + tid * 8 + rb8];
        mv[tid] += vv[tid] - r2 * s;
      }
      {
        const int unit = tid >> 2, q = tid & 3;
        const int r = unit >> 1, ss = unit & 1, tt = r >> 6, i = r & 63;
        float m0 = mu_t[0], m1 = mu_t[1], m2 = mu_t[2], m3 = mu_t[3];
        float dmx, dmy, c00, c01, c11;
        if (tt == 0 && ss == 0) {
          dmx = m0; dmy = m1;
          c00 = sg_t[0]; c01 = 0.5f * (sg_t[1] + sg_t[4]); c11 = sg_t[5];
        } else if (tt == 1 && ss == 1) {
          dmx = m2; dmy = m3;
          c00 = sg_t[10]; c01 = 0.5f * (sg_t[11] + sg_t[14]); c11 = sg_t[15];
        } else {
          dmx = 0.5f * (m0 + m2); dmy = 0.5f * (m1 + m3);
          float s00 = sg_t[0];
          float s02 = 0.5f * (sg_t[2] + sg_t[8]);
          float s22 = sg_t[10];
          float s01 = 0.5f * (sg_t[1] + sg_t[4]);
          float s03 = 0.5f * (sg_t[3] + sg_t[12]);
          float s21 = 0.5f * (sg_t[9] + sg_t[6]);
          float s23 = 0.5f * (sg_t[11] + sg_t[14]);
          float s11 = sg_t[5];
          float s13 = 0.5f * (sg_t[7] + sg_t[13]);
          float s33 = sg_t[15];
          c00 = 0.25f * (s00 + s02 + s02 + s22);
          c01 = 0.25f * (s01 + s03 + s21 + s23);
          c11 = 0.25f * (s11 + s13 + s13 + s33);
        }
        float D00 = 1.0001f + 2.0f * c00;
        float D01 = 2.0f * c01;
        float D11 = 1.0001f + 2.0f * c11;
        float det = D00 * D11 - D01 * D01;
        float dinv = 1.0f / det;
        float d00 = D11 * dinv, d01 = -D01 * dinv, d11 = D00 * dinv;
        float ldts = __logf(det);
        float cix = coords[2 * i], ciy = coords[2 * i + 1];
        const float* cj = coords + q * 32;
        float kv[16];
        float rsum = 0.0f;
        #pragma unroll
        for (int u = 0; u < 16; u++) {
          float dx = cix - cj[2 * u] - dmx;
          float dy = ciy - cj[2 * u + 1] - dmy;
          float qf = d00 * dx * dx + 2.0f * d01 * dx * dy + d11 * dy * dy;
          kv[u] = __expf(-0.5f * (qf + ldts));
          rsum += kv[u];
        }
        float rtot = rsum + __shfl_xor(rsum, 1);
        rtot += __shfl_xor(rtot, 2);
        float cv = (tt == 0) ? ((ss == 0) ? cpl00 : cpl01)
                             : ((ss == 0) ? cpl10 : cpl11);
        float norm = cv / fmaxf(rtot, 1e-6f);
        #pragma unroll
        for (int u = 0; u < 16; u++) kv[u] *= norm;
        if (ss == tt && ((i >> 4) == q)) kv[i & 15] += 1.0f - damping;
        unsigned short* arow = Ab + r * LDB + ss * 64 + q * 16;
        *(uint4*)(arow) = pack8(kv);
        *(uint4*)(arow + 8) = pack8(kv + 8);
      }
      __syncthreads();

      // ---- PHASE T: mfma T = A*P (full) + m = A*m GEMV ----
      {
        f32x4 acc[4];
        #pragma unroll
        for (int c = 0; c < 4; c++) acc[c] = (f32x4){0.0f, 0.0f, 0.0f, 0.0f};
        #pragma unroll
        for (int ks = 0; ks < 4; ks++) {
          const int ko = 32 * ks + 8 * quad;
          bf16x8 a = *(const bf16x8*)(Ab + (16 * rb + m16) * LDB + ko);
          #pragma unroll
          for (int ct = 0; ct < 4; ct++) {
            bf16x8 bb = *(const bf16x8*)(Pb + (64 * ch + 16 * ct + m16) * LDB + ko);
            acc[ct] = __builtin_amdgcn_mfma_f32_16x16x32_bf16(a, bb, acc[ct], 0, 0, 0);
          }
        }
        float newm = 0.0f;
        if (tid < DQ) {
          const unsigned* ar = (const unsigned*)(Ab + tid * LDB);
          #pragma unroll 8
          for (int k2 = 0; k2 < 64; k2++) {
            unsigned p = ar[k2];
            newm = fmaf(__uint_as_float(p << 16), mv[2 * k2], newm);
            newm = fmaf(__uint_as_float(p & 0xffff0000u), mv[2 * k2 + 1], newm);
          }
        }
        __syncthreads();
        #pragma unroll
        for (int ct = 0; ct < 4; ct++)
          #pragma unroll
          for (int reg = 0; reg < 4; reg++)
            Tb[(16 * rb + 4 * quad + reg) * LDB + 64 * ch + 16 * ct + m16] =
                f2bf(acc[ct][reg]);
        if (tid < DQ) mv[tid] = newm;
        __syncthreads();
      }

      // ---- PHASE P': mfma Sm = T*A^T + (q2+r2) I (lower tiles) -> Wf fp32 ----
      // (predicted P is never materialized: measurement uses only Sinv)
      {
        const int ctmax = rb - 4 * ch;
        f32x4 acc[4];
        #pragma unroll
        for (int c = 0; c < 4; c++) acc[c] = (f32x4){0.0f, 0.0f, 0.0f, 0.0f};
        if (ctmax >= 0) {
          #pragma unroll
          for (int ks = 0; ks < 4; ks++) {
            const int ko = 32 * ks + 8 * quad;
            bf16x8 a = *(const bf16x8*)(Tb + (16 * rb + m16) * LDB + ko);
            #pragma unroll
            for (int ct = 0; ct < 4; ct++) {
              if (ct <= ctmax) {
                bf16x8 bb = *(const bf16x8*)(Ab + (64 * ch + 16 * ct + m16) * LDB + ko);
                acc[ct] = __builtin_amdgcn_mfma_f32_16x16x32_bf16(a, bb, acc[ct], 0, 0, 0);
              }
            }
          }
        }
        __syncthreads();
        #pragma unroll
        for (int ct = 0; ct < 4; ct++) {
          if (ct <= ctmax) {
            #pragma unroll
            for (int reg = 0; reg < 4; reg++) {
              const int rg = 16 * rb + 4 * quad + reg;
              const int cgl = 64 * ch + 16 * ct + m16;
              Wf[rg * LDP + cgl] = acc[ct][reg] + ((rg == cgl) ? (q2 + r2) : 0.0f);
            }
          }
        }
        __syncthreads();
      }
    }

    // ================= measurement update =================
    // ---- PHASE K0: wave0 chol diag0 ; vv ----
    if (tid < 64) {
      chol16(Wf, mdiag, 0, lane);
    } else if (tid < 192) {
      const int i = tid - 64;
      vv[i] = zt[i] - mv[i];
    }
    __syncthreads();

    // ---- chol with lookahead ----
    #pragma unroll 1
    for (int kb = 0; kb < 7; kb++) {
      const int b0k = kb * 16, base = b0k + 16, nbelow = DQ - base;
      const int mb = 7 - kb;
      // panel TRSM: 8 threads/row, 2 output cols each. Row-sharing lanes are
      // in the same wave -> all row reads precede the stores (lockstep).
      if (tid < nbelow * 8) {
        const int r = base + (tid >> 3);
        const int jj = tid & 7;
        const float* wr = Wf + r * LDP + b0k;
        float w[16];
        #pragma unroll
        for (int u4 = 0; u4 < 4; u4++) {
          float4 w4 = *(const float4*)&wr[u4 * 4];
          w[u4*4] = w4.x; w[u4*4+1] = w4.y; w[u4*4+2] = w4.z; w[u4*4+3] = w4.w;
        }
        float o0 = w[jj] * mdiag[b0k + jj];
        for (int l = 0; l < jj; l++)
          o0 = fmaf(w[l], Wf[(b0k + l) * LDP + b0k + jj], o0);
        const int j2 = jj + 8;
        float o1 = w[j2] * mdiag[b0k + j2];
        for (int l = 0; l < j2; l++)
          o1 = fmaf(w[l], Wf[(b0k + l) * LDP + b0k + j2], o1);
        Wf[r * LDP + b0k + jj] = o0;
        Wf[r * LDP + b0k + j2] = o1;
      }
      __syncthreads();
      if (tid < 64) {
        #pragma unroll
        for (int u = 0; u < 4; u++) {
          const int o = lane * 4 + u;
          const int mr = o >> 4, mc = o & 15;
          if (mr >= mc) {
            const float* pi = Wf + (base + mr) * LDP + b0k;
            const float* pj = Wf + (base + mc) * LDP + b0k;
            float s = 0.0f;
            #pragma unroll
            for (int c4 = 0; c4 < 4; c4++) {
              float4 xa = *(const float4*)&pi[c4 * 4];
              float4 yb = *(const float4*)&pj[c4 * 4];
              s = fmaf(xa.x, yb.x, s); s = fmaf(xa.y, yb.y, s);
              s = fmaf(xa.z, yb.z, s); s = fmaf(xa.w, yb.w, s);
            }
            Wf[(base + mr) * LDP + base + mc] -= s;
          }
        }
        chol16(Wf, mdiag, base, lane);
      } else if (pbi < mb) {
        // trailing update: one 16x16 pair-tile per quad, 4x4 per lane.
        const int i0 = base + pbi * 16 + ((lane >> 2) & 3) * 4;
        const int j0 = base + pbj * 16 + (lane & 3) * 4;
        float a00=0.f,a01=0.f,a02=0.f,a03=0.f;
        float a10=0.f,a11=0.f,a12=0.f,a13=0.f;
        float a20=0.f,a21=0.f,a22=0.f,a23=0.f;
        float a30=0.f,a31=0.f,a32=0.f,a33=0.f;
        #pragma unroll
        for (int c4 = 0; c4 < 4; c4++) {
          const int co = b0k + 4 * c4;
          float4 x0 = *(const float4*)(Wf + (i0 + 0) * LDP + co);
          float4 x1 = *(const float4*)(Wf + (i0 + 1) * LDP + co);
          float4 x2 = *(const float4*)(Wf + (i0 + 2) * LDP + co);
          float4 x3 = *(const float4*)(Wf + (i0 + 3) * LDP + co);
          float4 y0 = *(const float4*)(Wf + (j0 + 0) * LDP + co);
          float4 y1 = *(const float4*)(Wf + (j0 + 1) * LDP + co);
          float4 y2 = *(const float4*)(Wf + (j0 + 2) * LDP + co);
          float4 y3 = *(const float4*)(Wf + (j0 + 3) * LDP + co);
          DOT4(a00,x0,y0); DOT4(a01,x0,y1); DOT4(a02,x0,y2); DOT4(a03,x0,y3);
          DOT4(a10,x1,y0); DOT4(a11,x1,y1); DOT4(a12,x1,y2); DOT4(a13,x1,y3);
          DOT4(a20,x2,y0); DOT4(a21,x2,y1); DOT4(a22,x2,y2); DOT4(a23,x2,y3);
          DOT4(a30,x3,y0); DOT4(a31,x3,y1); DOT4(a32,x3,y2); DOT4(a33,x3,y3);
        }
        float* w0 = Wf + (i0 + 0) * LDP + j0;
        float* w1 = Wf + (i0 + 1) * LDP + j0;
        float* w2 = Wf + (i0 + 2) * LDP + j0;
        float* w3 = Wf + (i0 + 3) * LDP + j0;
        w0[0] -= a00; w0[1] -= a01; w0[2] -= a02; w0[3] -= a03;
        w1[0] -= a10; w1[1] -= a11; w1[2] -= a12; w1[3] -= a13;
        w2[0] -= a20; w2[1] -= a21; w2[2] -= a22; w2[3] -= a23;
        w3[0] -= a30; w3[1] -= a31; w3[2] -= a32; w3[3] -= a33;
      }
      __syncthreads();
    }

    // ---- trinv (diagonal-distance): M into transposed-upper of Wf ----
    #pragma unroll 1
    for (int d = 1; d < 8; d++) {
      // phase 1: wave-per-pair, 2x2 register tile per lane.
      {
        const int Jp = wave;
        if (Jp + d < 8) {
          const int Ip = Jp + d;
          const int i16a = (lane >> 3) * 2;
          const int j16a = (lane & 7) * 2;
          const int rA = Ip * 16 + i16a;
          const int cA = Jp * 16 + j16a;
          const float mdA = mdiag[cA], mdB = mdiag[cA + 1];
          float g00 = 0.f, g01 = 0.f, g10 = 0.f, g11 = 0.f;
          const float* LrA = Wf + rA * LDP + Jp * 16;
          const float* LrB = LrA + LDP;
          const float* MrA = Wf + cA * LDP + Jp * 16;
          const float* MrB = MrA + LDP;
          #pragma unroll
          for (int c4 = 0; c4 < 4; c4++) {
            float4 l0 = *(const float4*)&LrA[4 * c4];
            float4 l1 = *(const float4*)&LrB[4 * c4];
            float4 ma = *(const float4*)&MrA[4 * c4];
            float4 mb4 = *(const float4*)&MrB[4 * c4];
            const int k0 = 4 * c4;
            const int jB = j16a + 1;
            float wa0 = (k0     > j16a) ? ma.x : ((k0     == j16a) ? mdA : 0.0f);
            float wa1 = (k0 + 1 > j16a) ? ma.y : ((k0 + 1 == j16a) ? mdA : 0.0f);
            float wa2 = (k0 + 2 > j16a) ? ma.z : ((k0 + 2 == j16a) ? mdA : 0.0f);
            float wa3 = (k0 + 3 > j16a) ? ma.w : ((k0 + 3 == j16a) ? mdA : 0.0f);
            float wb0 = (k0     > jB) ? mb4.x : ((k0     == jB) ? mdB : 0.0f);
            float wb1 = (k0 + 1 > jB) ? mb4.y : ((k0 + 1 == jB) ? mdB : 0.0f);
            float wb2 = (k0 + 2 > jB) ? mb4.z : ((k0 + 2 == jB) ? mdB : 0.0f);
            float wb3 = (k0 + 3 > jB) ? mb4.w : ((k0 + 3 == jB) ? mdB : 0.0f);
            g00 = fmaf(l0.x, wa0, fmaf(l0.y, wa1, fmaf(l0.z, wa2, fmaf(l0.w, wa3, g00))));
            g01 = fmaf(l0.x, wb0, fmaf(l0.y, wb1, fmaf(l0.z, wb2, fmaf(l0.w, wb3, g01))));
            g10 = fmaf(l1.x, wa0, fmaf(l1.y, wa1, fmaf(l1.z, wa2, fmaf(l1.w, wa3, g10))));
            g11 = fmaf(l1.x, wb0, fmaf(l1.y, wb1, fmaf(l1.z, wb2, fmaf(l1.w, wb3, g11))));
          }
          for (int K = Jp + 1; K < Ip; K++) {
            const float* LKa = Wf + rA * LDP + K * 16;
            const float* LKb = LKa + LDP;
            const float* MKa = Wf + cA * LDP + K * 16;
            const float* MKb = MKa + LDP;
            #pragma unroll
            for (int c4 = 0; c4 < 4; c4++) {
              float4 l0 = *(const float4*)&LKa[4 * c4];
              float4 l1 = *(const float4*)&LKb[4 * c4];
              float4 m0 = *(const float4*)&MKa[4 * c4];
              float4 m1 = *(const float4*)&MKb[4 * c4];
              DOT4(g00, l0, m0); DOT4(g01, l0, m1);
              DOT4(g10, l1, m0); DOT4(g11, l1, m1);
            }
          }
          float* gb = gtmp + Jp * 256 + i16a * 16 + j16a;
          gb[0] = g00; gb[1] = g01;
          gb[16] = g10; gb[17] = g11;
        }
      }
      __syncthreads();
      {
        const int z4 = tid >> 8;
        const int t8 = tid & 255;
        const int i16 = t8 >> 4, j16 = t8 & 15;
        for (int nb = z4; nb + d < 8; nb += 4) {
          const int J = nb, I = nb + d;
          const float* gb = gtmp + nb * 256;
          float s = mdiag[I * 16 + i16] * gb[i16 * 16 + j16];
          for (int k = 0; k < i16; k++)
            s = fmaf(Wf[(I * 16 + k) * LDP + I * 16 + i16], gb[k * 16 + j16], s);
          Wf[(J * 16 + j16) * LDP + (I * 16 + i16)] = -s;
        }
      }
      __syncthreads();
    }

    // ---- PHASE MC: y=Mv + logdet fold; convert M -> Mtb (staged) ----
    {
      const int mrow = tid >> 3, kc = (tid & 7) * 16;
      float mtv[16];
      if (kc > mrow) {
        const float4* rp = (const float4*)(Wf + mrow * LDP + kc);
        float4 q0 = rp[0], q1 = rp[1], q2v = rp[2], q3 = rp[3];
        mtv[0]=q0.x; mtv[1]=q0.y; mtv[2]=q0.z; mtv[3]=q0.w;
        mtv[4]=q1.x; mtv[5]=q1.y; mtv[6]=q1.z; mtv[7]=q1.w;
        mtv[8]=q2v.x; mtv[9]=q2v.y; mtv[10]=q2v.z; mtv[11]=q2v.w;
        mtv[12]=q3.x; mtv[13]=q3.y; mtv[14]=q3.z; mtv[15]=q3.w;
      } else if (kc + 15 < mrow) {
        #pragma unroll
        for (int u = 0; u < 16; u++) mtv[u] = 0.0f;
      } else {
        #pragma unroll
        for (int u = 0; u < 16; u++) {
          const int k = kc + u;
          mtv[u] = (k > mrow) ? Wf[mrow * LDP + k]
                 : ((k == mrow) ? mdiag[mrow] : 0.0f);
        }
      }
      if (tid < DQ) {
        nllp -= __logf(mdiag[tid]);
        float s = mdiag[tid] * vv[tid];
        for (int k = 0; k < tid; k++) s = fmaf(Wf[k * LDP + tid], vv[k], s);
        yv[tid] = s;
      }
      __syncthreads();
      unsigned short* mt = Mtb + mrow * LDB + kc;
      *(uint4*)(mt) = pack8(mtv);
      *(uint4*)(mt + 8) = pack8(mtv + 8);
      __syncthreads();
    }

    // ---- PHASE Pn: mfma Sinv = M^T*M (lower tiles); P = r2 I - r2^2 Sinv;
    //      (Sinv v) row partials for the deferred m-update merge ----
    {
      f32x4 acc[4];
      #pragma unroll
      for (int c = 0; c < 4; c++) acc[c] = (f32x4){0.0f, 0.0f, 0.0f, 0.0f};
      if (tid < DQ) nllp += 0.5f * yv[tid] * yv[tid];
      const int ctmax = rb - 4 * ch;
      if (ctmax >= 0) {
        for (int ks = (rb >> 1); ks < 4; ks++) {
          const int ko = 32 * ks + 8 * quad;
          bf16x8 a = *(const bf16x8*)(Mtb + (16 * rb + m16) * LDB + ko);
          #pragma unroll
          for (int ct = 0; ct < 4; ct++) {
            if (ct <= ctmax) {
              bf16x8 bb = *(const bf16x8*)(Mtb + (64 * ch + 16 * ct + m16) * LDB + ko);
              acc[ct] = __builtin_amdgcn_mfma_f32_16x16x32_bf16(a, bb, acc[ct], 0, 0, 0);
            }
          }
        }
      }
      // Pb = bf16(r2 I - r2^2 Sinv), mirror strict tiles (no alias w/ MFMA reads)
      const float nr22 = -r2 * r2;
      #pragma unroll
      for (int ct = 0; ct < 4; ct++) {
        if (ct <= ctmax) {
          const bool strict = (ct < ctmax);
          #pragma unroll
          for (int reg = 0; reg < 4; reg++) {
            const int rg = 16 * rb + 4 * quad + reg;
            const int cgl = 64 * ch + 16 * ct + m16;
            unsigned short hv = f2bf(nr22 * acc[ct][reg] + ((rg == cgl) ? r2 : 0.0f));
            Pb[rg * LDB + cgl] = hv;
            if (strict) Pb[cgl * LDB + rg] = hv;
          }
        }
      }
      // m-fold: (Sinv v) row partials (acc = Sinv, symmetric)
      {
        float s[4];
        #pragma unroll
        for (int reg = 0; reg < 4; reg++) {
          float tacc = 0.0f;
          #pragma unroll
          for (int ct = 0; ct < 4; ct++)
            if (ct <= ctmax)
              tacc += acc[ct][reg] * vv[64 * ch + 16 * ct + m16];
          #pragma unroll
          for (int off = 1; off < 16; off <<= 1) tacc += __shfl_xor(tacc, off);
          s[reg] = tacc;
        }
        if (m16 == 0) {
          #pragma unroll
          for (int reg = 0; reg < 4; reg++)
            gtmp[(16 * rb + 4 * quad + reg) * 2 + ch] = s[reg];
        }
        #pragma unroll
        for (int ct = 0; ct < 4; ct++) {
          float tacc = 0.0f;
          if (ct < ctmax) {   // strict-lower tiles only (avoid double count)
            #pragma unroll
            for (int reg = 0; reg < 4; reg++)
              tacc += acc[ct][reg] * vv[16 * rb + 4 * quad + reg];
          }
          tacc += __shfl_xor(tacc, 16);
          tacc += __shfl_xor(tacc, 32);
          if (quad == 0)
            gtmp[256 + (64 * ch + 16 * ct + m16) * 8 + rb] = tacc;
        }
      }
      __syncthreads();
    }
  }

  float total = block_reduce_sum(nllp, red);
  if (tid == 0)
    nll_out[b] = total + (float)TQ * 0.5f * (float)DQ * LOG2PI;
}

extern "C" __global__ void ide_finalize(const float* __restrict__ part,
                                        float* __restrict__ out) {
  if (threadIdx.x == 0) {
    float s = 0.0f;
    for (int i = 0; i < BQ; i++) s += part[i];
    out[0] = s * (1.0f / BQ);
  }
}

extern "C" void kernel_launch(void* const* d_in, const int* in_sizes, int n_in,
                              void* d_out, int out_size, void* d_ws, size_t ws_size,
                              hipStream_t stream) {
  (void)in_sizes; (void)n_in; (void)out_size; (void)ws_size;
  const float* z_seq        = (const float*)d_in[0];
  const float* site_lon     = (const float*)d_in[1];
  const float* site_lat     = (const float*)d_in[2];
  const float* mu_seq       = (const float*)d_in[3];
  const float* sigma_seq    = (const float*)d_in[4];
  const float* log_q        = (const float*)d_in[5];
  const float* log_r        = (const float*)d_in[6];
  const float* log_p0       = (const float*)d_in[7];
  const float* log_damp     = (const float*)d_in[8];
  const float* init_mean    = (const float*)d_in[9];
  const float* coupling_raw = (const float*)d_in[10];
  float* ws = (float*)d_ws;
  float* out = (float*)d_out;

  const size_t smem_bytes = (size_t)SMEM_FLOATS * sizeof(float);
  hipFuncSetAttribute((const void*)ide_kf_kernel,
                      hipFuncAttributeMaxDynamicSharedMemorySize,
                      (int)smem_bytes);

  hipLaunchKernelGGL(ide_kf_kernel, dim3(BQ), dim3(NTH), smem_bytes, stream,
                     z_seq, site_lon, site_lat, mu_seq, sigma_seq,
                     log_q, log_r, log_p0, log_damp, init_mean, coupling_raw,
                     ws);
  hipLaunchKernelGGL(ide_finalize, dim3(1), dim3(64), 0, stream, ws, out);
}

// Round 2
// 13556.207 us; speedup vs baseline: 1.1345x; 1.1345x over previous
//
#include <hip/hip_runtime.h>
#include <math.h>

// IDE state-space Kalman filter, MI355X (gfx950). Round 9:
// R7 structure (proven 14686 us) + R8 algebra only:
// - K = I - r2*Sinv identity (H=I, R=r2 I): Phase Y deleted; Pn = M^T M
//   (= Sm^-1) directly; P_new = r2 I - r2^2 Sinv; merge mv += vv - r2*(Sinv v).
// - P' writes only fp32 lower Sm (no bf16 predicted-P pack, no upper mirror).
// - MC gather vectorized (float4 per 16-col block); Mb pack dropped.
// R8's lane-concentrating rewrites (4x4 chol tiles, 8t/row TRSM, wave-per-pair
// trinv) REVERTED: they lengthened per-lane chains in a latency-bound kernel.

#define SQ 64
#define DQ 128
#define TQ 128
#define BQ 16
#define LDP 132           // fp32 row stride
#define LDB 136           // bf16 row stride (16B-aligned rows, 2-way banks)
#define WFLOATS 17408     // W region: 69632 B (holds 2 bf16 matrices)
#define NTH 1024
#define LOG2PI 1.8378770664093454f

#define SMEM_FLOATS 37520

typedef __attribute__((ext_vector_type(8))) short bf16x8;
typedef __attribute__((ext_vector_type(4))) float f32x4;

__device__ __forceinline__ unsigned short f2bf(float f) {
  unsigned u = __float_as_uint(f);
  u += 0x7fffu + ((u >> 16) & 1u);
  return (unsigned short)(u >> 16);
}
__device__ __forceinline__ float bf2f(unsigned short h) {
  return __uint_as_float(((unsigned)h) << 16);
}
__device__ __forceinline__ uint4 pack8(const float* v) {
  uint4 r;
  r.x = (unsigned)f2bf(v[0]) | ((unsigned)f2bf(v[1]) << 16);
  r.y = (unsigned)f2bf(v[2]) | ((unsigned)f2bf(v[3]) << 16);
  r.z = (unsigned)f2bf(v[4]) | ((unsigned)f2bf(v[5]) << 16);
  r.w = (unsigned)f2bf(v[6]) | ((unsigned)f2bf(v[7]) << 16);
  return r;
}

__device__ __forceinline__ float block_reduce_sum(float v, float* red) {
  #pragma unroll
  for (int off = 32; off > 0; off >>= 1) v += __shfl_down(v, off);
  const int tid = threadIdx.x;
  if ((tid & 63) == 0) red[tid >> 6] = v;
  __syncthreads();
  v = 0.0f;
  #pragma unroll
  for (int w = 0; w < NTH / 64; w++) v += red[w];
  __syncthreads();
  return v;
}

// 16x16 Cholesky + triangular inverse on wave 0 (register/shfl resident).
__device__ __forceinline__ void chol16(float* __restrict__ Wf,
                                       float* __restrict__ mdiag,
                                       int b0, int lane) {
  float a[16];
  if (lane < 16) {
    const float4* rp = (const float4*)(Wf + (b0 + lane) * LDP + b0);
    float4 q0 = rp[0], q1 = rp[1], q2v = rp[2], q3 = rp[3];
    a[0]=q0.x; a[1]=q0.y; a[2]=q0.z; a[3]=q0.w;
    a[4]=q1.x; a[5]=q1.y; a[6]=q1.z; a[7]=q1.w;
    a[8]=q2v.x; a[9]=q2v.y; a[10]=q2v.z; a[11]=q2v.w;
    a[12]=q3.x; a[13]=q3.y; a[14]=q3.z; a[15]=q3.w;
  } else {
    #pragma unroll
    for (int i = 0; i < 16; i++) a[i] = 1.0f;
  }
  float myrinv = 1.0f;
  #pragma unroll
  for (int j = 0; j < 16; j++) {
    float dj = __shfl(a[j], j);
    float rinv = rsqrtf(dj);
    float lij = a[j] * rinv;
    a[j] = lij;
    if (lane == j) myrinv = rinv;
    #pragma unroll
    for (int k = j + 1; k < 16; k++) {
      float lkj = __shfl(lij, k);
      a[k] = fmaf(-lij, lkj, a[k]);
    }
  }
  if (lane < 16) {
    float4* rp = (float4*)(Wf + (b0 + lane) * LDP + b0);
    rp[0] = make_float4(a[0], a[1], a[2], a[3]);
    rp[1] = make_float4(a[4], a[5], a[6], a[7]);
    rp[2] = make_float4(a[8], a[9], a[10], a[11]);
    rp[3] = make_float4(a[12], a[13], a[14], a[15]);
    mdiag[b0 + lane] = myrinv;
  }
  float x[16];
  #pragma unroll
  for (int i = 0; i < 16; i++) {
    float s = (i == lane) ? 1.0f : 0.0f;
    #pragma unroll
    for (int k = 0; k < 16; k++) {
      if (k < i) {
        float Lik = __shfl(a[k], i);
        s = fmaf(-Lik, x[k], s);
      }
    }
    float ri = __shfl(myrinv, i);
    x[i] = (i < lane) ? 0.0f : s * ri;
  }
  if (lane < 16) {
    #pragma unroll
    for (int i = 0; i < 16; i++)
      if (i > lane) Wf[(b0 + lane) * LDP + (b0 + i)] = x[i];
  }
}

extern "C" __global__ __launch_bounds__(NTH, 4)
void ide_kf_kernel(const float* __restrict__ z_seq,
                   const float* __restrict__ site_lon,
                   const float* __restrict__ site_lat,
                   const float* __restrict__ mu_seq,
                   const float* __restrict__ sigma_seq,
                   const float* __restrict__ log_q,
                   const float* __restrict__ log_r,
                   const float* __restrict__ log_p0,
                   const float* __restrict__ log_damp,
                   const float* __restrict__ init_mean,
                   const float* __restrict__ coupling_raw,
                   float* __restrict__ ws) {
  extern __shared__ float smem[];
  float* Wf     = smem;                  // 17408 floats (fp32 chol space)
  float* B1f    = Wf + WFLOATS;          // 8704 floats (Ab bf16)
  float* B2f    = B1f + 8704;            // 8704 floats (Pb bf16)
  float* gtmp   = B2f + 8704;            // 2048
  float* coords = gtmp + 2048;           // 128
  float* mv     = coords + 128;          // 128
  float* vv     = mv + DQ;               // 128
  float* yv     = vv + DQ;               // 128
  float* mdiag  = yv + DQ;               // 128
  float* red    = mdiag + DQ;            // 16

  unsigned short* Tb  = (unsigned short*)Wf;            // bf16, stride LDB
  unsigned short* Mtb = (unsigned short*)Wf;            // M^T row-major bf16
  unsigned short* Ab  = (unsigned short*)B1f;           // A bf16
  unsigned short* Pb  = (unsigned short*)B2f;           // P bf16 (symmetric)

  const int tid = threadIdx.x;
  const int lane = tid & 63;
  const int wave = tid >> 6;
  const int rb = wave >> 1, ch = wave & 1;
  const int m16 = lane & 15, quad = lane >> 4;
  const int b = blockIdx.x;
  float* nll_out = ws;

  const float r2 = __expf(2.0f * log_r[0]);
  const float q2 = __expf(2.0f * log_q[0]);
  const float p0sq = __expf(2.0f * log_p0[0]);
  const float damping = __expf(log_damp[0]);
  const float cpl00 = 1.0f + 0.25f * tanhf(coupling_raw[0]);
  const float cpl01 = 0.25f * tanhf(coupling_raw[1]);
  const float cpl10 = 0.25f * tanhf(coupling_raw[2]);
  const float cpl11 = 1.0f + 0.25f * tanhf(coupling_raw[3]);

  // ---- lon/lat projection ----
  float myLon = (tid < SQ) ? site_lon[tid] : 0.0f;
  float myLat = (tid < SQ) ? site_lat[tid] : 0.0f;
  float lat0 = block_reduce_sum(myLat, red) * (1.0f / 64.0f);
  float lon0 = block_reduce_sum(myLon, red) * (1.0f / 64.0f);
  if (tid < SQ) {
    const float km = 111.32f;
    float cs = cosf(lat0 * 0.017453292519943295f);
    coords[2 * tid]     = (myLon - lon0) * (km * cs);
    coords[2 * tid + 1] = (myLat - lat0) * km;
  }
  __syncthreads();
  float dsum = 0.0f, dcnt = 0.0f;
  for (int idx = tid; idx < SQ * SQ; idx += NTH) {
    int i = idx >> 6, j = idx & 63;
    float dx = coords[2 * i] - coords[2 * j];
    float dy = coords[2 * i + 1] - coords[2 * j + 1];
    float d = sqrtf(dx * dx + dy * dy + 1e-12f);
    dsum += d;
    if (d > 1e-6f) dcnt += 1.0f;
  }
  dsum = block_reduce_sum(dsum, red);
  dcnt = block_reduce_sum(dcnt, red);
  float scale = dsum / fmaxf(dcnt, 1.0f);
  float sdiv = 1.0f / fmaxf(scale, 1e-6f);
  if (tid < SQ) { coords[2 * tid] *= sdiv; coords[2 * tid + 1] *= sdiv; }

  // ---- init: Pb = bf16(p0sq I), Wf = (p0sq+r2) I, mv = init_mean ----
  for (int e = tid; e < WFLOATS / 4; e += NTH)
    ((float4*)Wf)[e] = make_float4(0.0f, 0.0f, 0.0f, 0.0f);
  for (int e = tid; e < 8704 / 4; e += NTH)
    ((float4*)B2f)[e] = make_float4(0.0f, 0.0f, 0.0f, 0.0f);
  __syncthreads();
  if (tid < DQ) {
    Wf[tid * LDP + tid] = p0sq + r2;
    Pb[tid * LDB + tid] = f2bf(p0sq);
    mv[tid] = init_mean[tid];
  }
  __syncthreads();

  float nllp = 0.0f;

  #pragma unroll 1
  for (int t = 0; t < TQ; t++) {
    const float* zt = z_seq + ((size_t)b * TQ + t) * DQ;

    if (t > 0) {
      const float* mu_t = mu_seq + ((size_t)b * (TQ - 1) + (t - 1)) * 4;
      const float* sg_t = sigma_seq + ((size_t)b * (TQ - 1) + (t - 1)) * 16;

      // ---- PHASE A: merge m-update partials + build A -> Ab (bf16) ----
      // m_new = m' + v - r2 * (Sinv v); partials s hold (Sinv v) pieces.
      if (tid < DQ) {
        float s = gtmp[2 * tid] + gtmp[2 * tid + 1];
        #pragma unroll
        for (int rb8 = 0; rb8 < 8; rb8++) s += gtmp[256 + tid * 8 + rb8];
        mv[tid] += vv[tid] - r2 * s;
      }
      {
        const int unit = tid >> 2, q = tid & 3;
        const int r = unit >> 1, ss = unit & 1, tt = r >> 6, i = r & 63;
        float m0 = mu_t[0], m1 = mu_t[1], m2 = mu_t[2], m3 = mu_t[3];
        float dmx, dmy, c00, c01, c11;
        if (tt == 0 && ss == 0) {
          dmx = m0; dmy = m1;
          c00 = sg_t[0]; c01 = 0.5f * (sg_t[1] + sg_t[4]); c11 = sg_t[5];
        } else if (tt == 1 && ss == 1) {
          dmx = m2; dmy = m3;
          c00 = sg_t[10]; c01 = 0.5f * (sg_t[11] + sg_t[14]); c11 = sg_t[15];
        } else {
          dmx = 0.5f * (m0 + m2); dmy = 0.5f * (m1 + m3);
          float s00 = sg_t[0];
          float s02 = 0.5f * (sg_t[2] + sg_t[8]);
          float s22 = sg_t[10];
          float s01 = 0.5f * (sg_t[1] + sg_t[4]);
          float s03 = 0.5f * (sg_t[3] + sg_t[12]);
          float s21 = 0.5f * (sg_t[9] + sg_t[6]);
          float s23 = 0.5f * (sg_t[11] + sg_t[14]);
          float s11 = sg_t[5];
          float s13 = 0.5f * (sg_t[7] + sg_t[13]);
          float s33 = sg_t[15];
          c00 = 0.25f * (s00 + s02 + s02 + s22);
          c01 = 0.25f * (s01 + s03 + s21 + s23);
          c11 = 0.25f * (s11 + s13 + s13 + s33);
        }
        float D00 = 1.0001f + 2.0f * c00;
        float D01 = 2.0f * c01;
        float D11 = 1.0001f + 2.0f * c11;
        float det = D00 * D11 - D01 * D01;
        float dinv = 1.0f / det;
        float d00 = D11 * dinv, d01 = -D01 * dinv, d11 = D00 * dinv;
        float ldts = __logf(det);
        float cix = coords[2 * i], ciy = coords[2 * i + 1];
        const float* cj = coords + q * 32;
        float kv[16];
        float rsum = 0.0f;
        #pragma unroll
        for (int u = 0; u < 16; u++) {
          float dx = cix - cj[2 * u] - dmx;
          float dy = ciy - cj[2 * u + 1] - dmy;
          float qf = d00 * dx * dx + 2.0f * d01 * dx * dy + d11 * dy * dy;
          kv[u] = __expf(-0.5f * (qf + ldts));
          rsum += kv[u];
        }
        float rtot = rsum + __shfl_xor(rsum, 1);
        rtot += __shfl_xor(rtot, 2);
        float cv = (tt == 0) ? ((ss == 0) ? cpl00 : cpl01)
                             : ((ss == 0) ? cpl10 : cpl11);
        float norm = cv / fmaxf(rtot, 1e-6f);
        #pragma unroll
        for (int u = 0; u < 16; u++) kv[u] *= norm;
        if (ss == tt && ((i >> 4) == q)) kv[i & 15] += 1.0f - damping;
        unsigned short* arow = Ab + r * LDB + ss * 64 + q * 16;
        *(uint4*)(arow) = pack8(kv);
        *(uint4*)(arow + 8) = pack8(kv + 8);
      }
      __syncthreads();

      // ---- PHASE T: mfma T = A*P (full) + m = A*m GEMV ----
      {
        f32x4 acc[4];
        #pragma unroll
        for (int c = 0; c < 4; c++) acc[c] = (f32x4){0.0f, 0.0f, 0.0f, 0.0f};
        #pragma unroll
        for (int ks = 0; ks < 4; ks++) {
          const int ko = 32 * ks + 8 * quad;
          bf16x8 a = *(const bf16x8*)(Ab + (16 * rb + m16) * LDB + ko);
          #pragma unroll
          for (int ct = 0; ct < 4; ct++) {
            bf16x8 bb = *(const bf16x8*)(Pb + (64 * ch + 16 * ct + m16) * LDB + ko);
            acc[ct] = __builtin_amdgcn_mfma_f32_16x16x32_bf16(a, bb, acc[ct], 0, 0, 0);
          }
        }
        float newm = 0.0f;
        if (tid < DQ) {
          const unsigned* ar = (const unsigned*)(Ab + tid * LDB);
          #pragma unroll 8
          for (int k2 = 0; k2 < 64; k2++) {
            unsigned p = ar[k2];
            newm = fmaf(__uint_as_float(p << 16), mv[2 * k2], newm);
            newm = fmaf(__uint_as_float(p & 0xffff0000u), mv[2 * k2 + 1], newm);
          }
        }
        __syncthreads();
        #pragma unroll
        for (int ct = 0; ct < 4; ct++)
          #pragma unroll
          for (int reg = 0; reg < 4; reg++)
            Tb[(16 * rb + 4 * quad + reg) * LDB + 64 * ch + 16 * ct + m16] =
                f2bf(acc[ct][reg]);
        if (tid < DQ) mv[tid] = newm;
        __syncthreads();
      }

      // ---- PHASE P': mfma Sm = T*A^T + (q2+r2) I (lower tiles) -> Wf fp32 ----
      // (predicted P is never materialized: measurement uses only Sinv)
      {
        const int ctmax = rb - 4 * ch;
        f32x4 acc[4];
        #pragma unroll
        for (int c = 0; c < 4; c++) acc[c] = (f32x4){0.0f, 0.0f, 0.0f, 0.0f};
        if (ctmax >= 0) {
          #pragma unroll
          for (int ks = 0; ks < 4; ks++) {
            const int ko = 32 * ks + 8 * quad;
            bf16x8 a = *(const bf16x8*)(Tb + (16 * rb + m16) * LDB + ko);
            #pragma unroll
            for (int ct = 0; ct < 4; ct++) {
              if (ct <= ctmax) {
                bf16x8 bb = *(const bf16x8*)(Ab + (64 * ch + 16 * ct + m16) * LDB + ko);
                acc[ct] = __builtin_amdgcn_mfma_f32_16x16x32_bf16(a, bb, acc[ct], 0, 0, 0);
              }
            }
          }
        }
        __syncthreads();
        #pragma unroll
        for (int ct = 0; ct < 4; ct++) {
          if (ct <= ctmax) {
            #pragma unroll
            for (int reg = 0; reg < 4; reg++) {
              const int rg = 16 * rb + 4 * quad + reg;
              const int cgl = 64 * ch + 16 * ct + m16;
              Wf[rg * LDP + cgl] = acc[ct][reg] + ((rg == cgl) ? (q2 + r2) : 0.0f);
            }
          }
        }
        __syncthreads();
      }
    }

    // ================= measurement update =================
    // ---- PHASE K0: wave0 chol diag0 ; vv ----
    if (tid < 64) {
      chol16(Wf, mdiag, 0, lane);
    } else if (tid < 192) {
      const int i = tid - 64;
      vv[i] = zt[i] - mv[i];
    }
    __syncthreads();

    // ---- chol with lookahead (R5/R7 form) ----
    #pragma unroll 1
    for (int kb = 0; kb < 7; kb++) {
      const int b0k = kb * 16, base = b0k + 16, nbelow = DQ - base;
      if (tid < nbelow) {
        const int r = base + tid;
        float* wr = Wf + r * LDP + b0k;
        float w[16];
        #pragma unroll
        for (int u4 = 0; u4 < 4; u4++) {
          float4 w4 = *(const float4*)&wr[u4 * 4];
          w[u4*4] = w4.x; w[u4*4+1] = w4.y; w[u4*4+2] = w4.z; w[u4*4+3] = w4.w;
        }
        float out[16];
        #pragma unroll
        for (int j = 0; j < 16; j++) {
          float s = w[j] * mdiag[b0k + j];
          #pragma unroll
          for (int l = 0; l < 16; l++) {
            if (l < j) s = fmaf(w[l], Wf[(b0k + l) * LDP + b0k + j], s);
          }
          out[j] = s;
        }
        #pragma unroll
        for (int u4 = 0; u4 < 4; u4++)
          *(float4*)&wr[u4 * 4] =
              make_float4(out[u4*4], out[u4*4+1], out[u4*4+2], out[u4*4+3]);
      }
      __syncthreads();
      if (tid < 64) {
        #pragma unroll
        for (int u = 0; u < 4; u++) {
          const int o = lane * 4 + u;
          const int mr = o >> 4, mc = o & 15;
          if (mr >= mc) {
            const float* pi = Wf + (base + mr) * LDP + b0k;
            const float* pj = Wf + (base + mc) * LDP + b0k;
            float s = 0.0f;
            #pragma unroll
            for (int c4 = 0; c4 < 4; c4++) {
              float4 xa = *(const float4*)&pi[c4 * 4];
              float4 yb = *(const float4*)&pj[c4 * 4];
              s = fmaf(xa.x, yb.x, s); s = fmaf(xa.y, yb.y, s);
              s = fmaf(xa.z, yb.z, s); s = fmaf(xa.w, yb.w, s);
            }
            Wf[(base + mr) * LDP + base + mc] -= s;
          }
        }
        chol16(Wf, mdiag, base, lane);
      } else if (tid >= 256) {
        const int grp = (tid >> 8) - 1;
        const int t8 = tid & 255;
        const int mrow = t8 >> 4, mcol = t8 & 15;
        const int mb = 7 - kb;
        int cnt = 0;
        for (int bi = 0; bi < mb; bi++) {
          for (int bj = 0; bj <= bi; bj++) {
            if (bi | bj) {
              if (cnt % 3 == grp && (bi > bj || mrow >= mcol)) {
                const int i = base + bi * 16 + mrow;
                const int j = base + bj * 16 + mcol;
                const float* pi = Wf + i * LDP + b0k;
                const float* pj = Wf + j * LDP + b0k;
                float s = 0.0f;
                #pragma unroll
                for (int c4 = 0; c4 < 4; c4++) {
                  float4 xa = *(const float4*)&pi[c4 * 4];
                  float4 yb = *(const float4*)&pj[c4 * 4];
                  s = fmaf(xa.x, yb.x, s); s = fmaf(xa.y, yb.y, s);
                  s = fmaf(xa.z, yb.z, s); s = fmaf(xa.w, yb.w, s);
                }
                Wf[i * LDP + j] -= s;
              }
              cnt++;
            }
          }
        }
      }
      __syncthreads();
    }

    // ---- trinv (R5/R7 diagonal-distance): M into transposed-upper of Wf ----
    #pragma unroll 1
    for (int d = 1; d < 8; d++) {
      const int z4 = tid >> 8;
      const int t8 = tid & 255;
      const int i16 = t8 >> 4, j16 = t8 & 15;
      for (int nb = z4; nb + d < 8; nb += 4) {
        const int J = nb, I = nb + d;
        const float* Lrow = Wf + (I * 16 + i16) * LDP + J * 16;
        const float* Mrow = Wf + (J * 16 + j16) * LDP + J * 16;
        const float md = mdiag[J * 16 + j16];
        float g = 0.0f;
        #pragma unroll
        for (int c4 = 0; c4 < 4; c4++) {
          float4 lv = *(const float4*)&Lrow[c4 * 4];
          float4 mq = *(const float4*)&Mrow[c4 * 4];
          float w0 = (c4*4+0 > j16) ? mq.x : ((c4*4+0 == j16) ? md : 0.0f);
          float w1 = (c4*4+1 > j16) ? mq.y : ((c4*4+1 == j16) ? md : 0.0f);
          float w2 = (c4*4+2 > j16) ? mq.z : ((c4*4+2 == j16) ? md : 0.0f);
          float w3 = (c4*4+3 > j16) ? mq.w : ((c4*4+3 == j16) ? md : 0.0f);
          g = fmaf(lv.x, w0, g); g = fmaf(lv.y, w1, g);
          g = fmaf(lv.z, w2, g); g = fmaf(lv.w, w3, g);
        }
        for (int K = J + 1; K < I; K++) {
          const float* LK = Lrow + (K - J) * 16;
          const float* MK = Wf + (J * 16 + j16) * LDP + K * 16;
          #pragma unroll
          for (int c4 = 0; c4 < 4; c4++) {
            float4 lv = *(const float4*)&LK[c4 * 4];
            float4 mq = *(const float4*)&MK[c4 * 4];
            g = fmaf(lv.x, mq.x, g); g = fmaf(lv.y, mq.y, g);
            g = fmaf(lv.z, mq.z, g); g = fmaf(lv.w, mq.w, g);
          }
        }
        gtmp[nb * 256 + t8] = g;
      }
      __syncthreads();
      for (int nb = z4; nb + d < 8; nb += 4) {
        const int J = nb, I = nb + d;
        const float* gb = gtmp + nb * 256;
        float s = mdiag[I * 16 + i16] * gb[i16 * 16 + j16];
        for (int k = 0; k < i16; k++)
          s = fmaf(Wf[(I * 16 + k) * LDP + I * 16 + i16], gb[k * 16 + j16], s);
        Wf[(J * 16 + j16) * LDP + (I * 16 + i16)] = -s;
      }
      __syncthreads();
    }

    // ---- PHASE MC: y=Mv + logdet fold; convert M -> Mtb (staged) ----
    {
      const int mrow = tid >> 3, kc = (tid & 7) * 16;
      float mtv[16];
      if (kc > mrow) {
        const float4* rp = (const float4*)(Wf + mrow * LDP + kc);
        float4 q0 = rp[0], q1 = rp[1], q2v = rp[2], q3 = rp[3];
        mtv[0]=q0.x; mtv[1]=q0.y; mtv[2]=q0.z; mtv[3]=q0.w;
        mtv[4]=q1.x; mtv[5]=q1.y; mtv[6]=q1.z; mtv[7]=q1.w;
        mtv[8]=q2v.x; mtv[9]=q2v.y; mtv[10]=q2v.z; mtv[11]=q2v.w;
        mtv[12]=q3.x; mtv[13]=q3.y; mtv[14]=q3.z; mtv[15]=q3.w;
      } else if (kc + 15 < mrow) {
        #pragma unroll
        for (int u = 0; u < 16; u++) mtv[u] = 0.0f;
      } else {
        #pragma unroll
        for (int u = 0; u < 16; u++) {
          const int k = kc + u;
          mtv[u] = (k > mrow) ? Wf[mrow * LDP + k]
                 : ((k == mrow) ? mdiag[mrow] : 0.0f);
        }
      }
      if (tid < DQ) {
        nllp -= __logf(mdiag[tid]);
        float s = mdiag[tid] * vv[tid];
        for (int k = 0; k < tid; k++) s = fmaf(Wf[k * LDP + tid], vv[k], s);
        yv[tid] = s;
      }
      __syncthreads();
      unsigned short* mt = Mtb + mrow * LDB + kc;
      *(uint4*)(mt) = pack8(mtv);
      *(uint4*)(mt + 8) = pack8(mtv + 8);
      __syncthreads();
    }

    // ---- PHASE Pn: mfma Sinv = M^T*M (lower tiles); P = r2 I - r2^2 Sinv;
    //      (Sinv v) row partials for the deferred m-update merge ----
    {
      f32x4 acc[4];
      #pragma unroll
      for (int c = 0; c < 4; c++) acc[c] = (f32x4){0.0f, 0.0f, 0.0f, 0.0f};
      if (tid < DQ) nllp += 0.5f * yv[tid] * yv[tid];
      const int ctmax = rb - 4 * ch;
      if (ctmax >= 0) {
        for (int ks = (rb >> 1); ks < 4; ks++) {
          const int ko = 32 * ks + 8 * quad;
          bf16x8 a = *(const bf16x8*)(Mtb + (16 * rb + m16) * LDB + ko);
          #pragma unroll
          for (int ct = 0; ct < 4; ct++) {
            if (ct <= ctmax) {
              bf16x8 bb = *(const bf16x8*)(Mtb + (64 * ch + 16 * ct + m16) * LDB + ko);
              acc[ct] = __builtin_amdgcn_mfma_f32_16x16x32_bf16(a, bb, acc[ct], 0, 0, 0);
            }
          }
        }
      }
      // Pb = bf16(r2 I - r2^2 Sinv), mirror strict tiles (no alias w/ MFMA reads)
      const float nr22 = -r2 * r2;
      #pragma unroll
      for (int ct = 0; ct < 4; ct++) {
        if (ct <= ctmax) {
          const bool strict = (ct < ctmax);
          #pragma unroll
          for (int reg = 0; reg < 4; reg++) {
            const int rg = 16 * rb + 4 * quad + reg;
            const int cgl = 64 * ch + 16 * ct + m16;
            unsigned short hv = f2bf(nr22 * acc[ct][reg] + ((rg == cgl) ? r2 : 0.0f));
            Pb[rg * LDB + cgl] = hv;
            if (strict) Pb[cgl * LDB + rg] = hv;
          }
        }
      }
      // m-fold: (Sinv v) row partials (acc = Sinv, symmetric)
      {
        float s[4];
        #pragma unroll
        for (int reg = 0; reg < 4; reg++) {
          float tacc = 0.0f;
          #pragma unroll
          for (int ct = 0; ct < 4; ct++)
            if (ct <= ctmax)
              tacc += acc[ct][reg] * vv[64 * ch + 16 * ct + m16];
          #pragma unroll
          for (int off = 1; off < 16; off <<= 1) tacc += __shfl_xor(tacc, off);
          s[reg] = tacc;
        }
        if (m16 == 0) {
          #pragma unroll
          for (int reg = 0; reg < 4; reg++)
            gtmp[(16 * rb + 4 * quad + reg) * 2 + ch] = s[reg];
        }
        #pragma unroll
        for (int ct = 0; ct < 4; ct++) {
          float tacc = 0.0f;
          if (ct < ctmax) {   // strict-lower tiles only (avoid double count)
            #pragma unroll
            for (int reg = 0; reg < 4; reg++)
              tacc += acc[ct][reg] * vv[16 * rb + 4 * quad + reg];
          }
          tacc += __shfl_xor(tacc, 16);
          tacc += __shfl_xor(tacc, 32);
          if (quad == 0)
            gtmp[256 + (64 * ch + 16 * ct + m16) * 8 + rb] = tacc;
        }
      }
      __syncthreads();
    }
  }

  float total = block_reduce_sum(nllp, red);
  if (tid == 0)
    nll_out[b] = total + (float)TQ * 0.5f * (float)DQ * LOG2PI;
}

extern "C" __global__ void ide_finalize(const float* __restrict__ part,
                                        float* __restrict__ out) {
  if (threadIdx.x == 0) {
    float s = 0.0f;
    for (int i = 0; i < BQ; i++) s += part[i];
    out[0] = s * (1.0f / BQ);
  }
}

extern "C" void kernel_launch(void* const* d_in, const int* in_sizes, int n_in,
                              void* d_out, int out_size, void* d_ws, size_t ws_size,
                              hipStream_t stream) {
  (void)in_sizes; (void)n_in; (void)out_size; (void)ws_size;
  const float* z_seq        = (const float*)d_in[0];
  const float* site_lon     = (const float*)d_in[1];
  const float* site_lat     = (const float*)d_in[2];
  const float* mu_seq       = (const float*)d_in[3];
  const float* sigma_seq    = (const float*)d_in[4];
  const float* log_q        = (const float*)d_in[5];
  const float* log_r        = (const float*)d_in[6];
  const float* log_p0       = (const float*)d_in[7];
  const float* log_damp     = (const float*)d_in[8];
  const float* init_mean    = (const float*)d_in[9];
  const float* coupling_raw = (const float*)d_in[10];
  float* ws = (float*)d_ws;
  float* out = (float*)d_out;

  const size_t smem_bytes = (size_t)SMEM_FLOATS * sizeof(float);
  hipFuncSetAttribute((const void*)ide_kf_kernel,
                      hipFuncAttributeMaxDynamicSharedMemorySize,
                      (int)smem_bytes);

  hipLaunchKernelGGL(ide_kf_kernel, dim3(BQ), dim3(NTH), smem_bytes, stream,
                     z_seq, site_lon, site_lat, mu_seq, sigma_seq,
                     log_q, log_r, log_p0, log_damp, init_mean, coupling_raw,
                     ws);
  hipLaunchKernelGGL(ide_finalize, dim3(1), dim3(64), 0, stream, ws, out);
}

// Round 3
// 10717.336 us; speedup vs baseline: 1.4350x; 1.2649x over previous
//
#include <hip/hip_runtime.h>
#include <math.h>

// IDE state-space Kalman filter, MI355X (gfx950). Round 10:
// R9 (13556 us) + phase-structure reduction (37 -> 28 barriers/step):
// - trinv fused: i16-fast lane remap; Linv_II applied in-register via
//   intra-wave shfl (no gtmp round-trip, no mid-barrier): 14 -> 7 barriers.
// - chol16 x-solve hoisted: wave1 inverts diag block kb concurrently with
//   wave0's chol16(kb+1); only block 7 keeps in-chol16 x-solve (kb==6).
// - Mtb relocated to B1f (dead Ab region): MC loses aliasing mid-barrier.
// - Pn m-fold replaced by GEMV Sinv*v = Mtb . yv (same bf16xfp32 precision),
//   Phase-A merge reads one float from gtmp.
// - m ping-pong (mv/mv2): Phase T loses its mid-barrier.

#define SQ 64
#define DQ 128
#define TQ 128
#define BQ 16
#define LDP 132           // fp32 row stride
#define LDB 136           // bf16 row stride (16B-aligned rows, 2-way banks)
#define WFLOATS 17408     // W region: 69632 B
#define NTH 1024
#define LOG2PI 1.8378770664093454f

#define SMEM_FLOATS 37648

typedef __attribute__((ext_vector_type(8))) short bf16x8;
typedef __attribute__((ext_vector_type(4))) float f32x4;

__device__ __forceinline__ unsigned short f2bf(float f) {
  unsigned u = __float_as_uint(f);
  u += 0x7fffu + ((u >> 16) & 1u);
  return (unsigned short)(u >> 16);
}
__device__ __forceinline__ uint4 pack8(const float* v) {
  uint4 r;
  r.x = (unsigned)f2bf(v[0]) | ((unsigned)f2bf(v[1]) << 16);
  r.y = (unsigned)f2bf(v[2]) | ((unsigned)f2bf(v[3]) << 16);
  r.z = (unsigned)f2bf(v[4]) | ((unsigned)f2bf(v[5]) << 16);
  r.w = (unsigned)f2bf(v[6]) | ((unsigned)f2bf(v[7]) << 16);
  return r;
}

__device__ __forceinline__ float block_reduce_sum(float v, float* red) {
  #pragma unroll
  for (int off = 32; off > 0; off >>= 1) v += __shfl_down(v, off);
  const int tid = threadIdx.x;
  if ((tid & 63) == 0) red[tid >> 6] = v;
  __syncthreads();
  v = 0.0f;
  #pragma unroll
  for (int w = 0; w < NTH / 64; w++) v += red[w];
  __syncthreads();
  return v;
}

// 16x16 Cholesky on wave 0 (register/shfl resident). x-solve (Linv block)
// only when do_x (last block); other blocks inverted by wave1 concurrently.
__device__ __forceinline__ void chol16(float* __restrict__ Wf,
                                       float* __restrict__ mdiag,
                                       int b0, int lane, bool do_x) {
  float a[16];
  if (lane < 16) {
    const float4* rp = (const float4*)(Wf + (b0 + lane) * LDP + b0);
    float4 q0 = rp[0], q1 = rp[1], q2v = rp[2], q3 = rp[3];
    a[0]=q0.x; a[1]=q0.y; a[2]=q0.z; a[3]=q0.w;
    a[4]=q1.x; a[5]=q1.y; a[6]=q1.z; a[7]=q1.w;
    a[8]=q2v.x; a[9]=q2v.y; a[10]=q2v.z; a[11]=q2v.w;
    a[12]=q3.x; a[13]=q3.y; a[14]=q3.z; a[15]=q3.w;
  } else {
    #pragma unroll
    for (int i = 0; i < 16; i++) a[i] = 1.0f;
  }
  float myrinv = 1.0f;
  #pragma unroll
  for (int j = 0; j < 16; j++) {
    float dj = __shfl(a[j], j);
    float rinv = rsqrtf(dj);
    float lij = a[j] * rinv;
    a[j] = lij;
    if (lane == j) myrinv = rinv;
    #pragma unroll
    for (int k = j + 1; k < 16; k++) {
      float lkj = __shfl(lij, k);
      a[k] = fmaf(-lij, lkj, a[k]);
    }
  }
  if (lane < 16) {
    float4* rp = (float4*)(Wf + (b0 + lane) * LDP + b0);
    rp[0] = make_float4(a[0], a[1], a[2], a[3]);
    rp[1] = make_float4(a[4], a[5], a[6], a[7]);
    rp[2] = make_float4(a[8], a[9], a[10], a[11]);
    rp[3] = make_float4(a[12], a[13], a[14], a[15]);
    mdiag[b0 + lane] = myrinv;
  }
  if (do_x) {
    float x[16];
    #pragma unroll
    for (int i = 0; i < 16; i++) {
      float s = (i == lane) ? 1.0f : 0.0f;
      #pragma unroll
      for (int k = 0; k < 16; k++) {
        if (k < i) {
          float Lik = __shfl(a[k], i);
          s = fmaf(-Lik, x[k], s);
        }
      }
      float ri = __shfl(myrinv, i);
      x[i] = (i < lane) ? 0.0f : s * ri;
    }
    if (lane < 16) {
      #pragma unroll
      for (int i = 0; i < 16; i++)
        if (i > lane) Wf[(b0 + lane) * LDP + (b0 + i)] = x[i];
    }
  }
}

extern "C" __global__ __launch_bounds__(NTH, 4)
void ide_kf_kernel(const float* __restrict__ z_seq,
                   const float* __restrict__ site_lon,
                   const float* __restrict__ site_lat,
                   const float* __restrict__ mu_seq,
                   const float* __restrict__ sigma_seq,
                   const float* __restrict__ log_q,
                   const float* __restrict__ log_r,
                   const float* __restrict__ log_p0,
                   const float* __restrict__ log_damp,
                   const float* __restrict__ init_mean,
                   const float* __restrict__ coupling_raw,
                   float* __restrict__ ws) {
  extern __shared__ float smem[];
  float* Wf     = smem;                  // 17408 floats (fp32 chol space)
  float* B1f    = Wf + WFLOATS;          // 8704 floats (Ab / Mtb bf16)
  float* B2f    = B1f + 8704;            // 8704 floats (Pb bf16)
  float* gtmp   = B2f + 8704;            // 2048 (only [0,128) used now)
  float* coords = gtmp + 2048;           // 128
  float* mv     = coords + 128;          // 128
  float* mv2    = mv + DQ;               // 128
  float* vv     = mv2 + DQ;              // 128
  float* yv     = vv + DQ;               // 128
  float* mdiag  = yv + DQ;               // 128
  float* red    = mdiag + DQ;            // 16

  unsigned short* Tb  = (unsigned short*)Wf;            // bf16, stride LDB
  unsigned short* Ab  = (unsigned short*)B1f;           // A bf16
  unsigned short* Mtb = (unsigned short*)B1f;           // M^T bf16 (after P' consumed A)
  unsigned short* Pb  = (unsigned short*)B2f;           // P bf16 (symmetric)

  const int tid = threadIdx.x;
  const int lane = tid & 63;
  const int wave = tid >> 6;
  const int rb = wave >> 1, ch = wave & 1;
  const int m16 = lane & 15, quad = lane >> 4;
  const int b = blockIdx.x;
  float* nll_out = ws;

  const float r2 = __expf(2.0f * log_r[0]);
  const float q2 = __expf(2.0f * log_q[0]);
  const float p0sq = __expf(2.0f * log_p0[0]);
  const float damping = __expf(log_damp[0]);
  const float cpl00 = 1.0f + 0.25f * tanhf(coupling_raw[0]);
  const float cpl01 = 0.25f * tanhf(coupling_raw[1]);
  const float cpl10 = 0.25f * tanhf(coupling_raw[2]);
  const float cpl11 = 1.0f + 0.25f * tanhf(coupling_raw[3]);

  // ---- lon/lat projection ----
  float myLon = (tid < SQ) ? site_lon[tid] : 0.0f;
  float myLat = (tid < SQ) ? site_lat[tid] : 0.0f;
  float lat0 = block_reduce_sum(myLat, red) * (1.0f / 64.0f);
  float lon0 = block_reduce_sum(myLon, red) * (1.0f / 64.0f);
  if (tid < SQ) {
    const float km = 111.32f;
    float cs = cosf(lat0 * 0.017453292519943295f);
    coords[2 * tid]     = (myLon - lon0) * (km * cs);
    coords[2 * tid + 1] = (myLat - lat0) * km;
  }
  __syncthreads();
  float dsum = 0.0f, dcnt = 0.0f;
  for (int idx = tid; idx < SQ * SQ; idx += NTH) {
    int i = idx >> 6, j = idx & 63;
    float dx = coords[2 * i] - coords[2 * j];
    float dy = coords[2 * i + 1] - coords[2 * j + 1];
    float d = sqrtf(dx * dx + dy * dy + 1e-12f);
    dsum += d;
    if (d > 1e-6f) dcnt += 1.0f;
  }
  dsum = block_reduce_sum(dsum, red);
  dcnt = block_reduce_sum(dcnt, red);
  float scale = dsum / fmaxf(dcnt, 1.0f);
  float sdiv = 1.0f / fmaxf(scale, 1e-6f);
  if (tid < SQ) { coords[2 * tid] *= sdiv; coords[2 * tid + 1] *= sdiv; }

  // ---- init: Pb = bf16(p0sq I), Wf = (p0sq+r2) I, mv = init_mean ----
  for (int e = tid; e < WFLOATS / 4; e += NTH)
    ((float4*)Wf)[e] = make_float4(0.0f, 0.0f, 0.0f, 0.0f);
  for (int e = tid; e < 8704 / 4; e += NTH)
    ((float4*)B2f)[e] = make_float4(0.0f, 0.0f, 0.0f, 0.0f);
  __syncthreads();
  if (tid < DQ) {
    Wf[tid * LDP + tid] = p0sq + r2;
    Pb[tid * LDB + tid] = f2bf(p0sq);
    mv[tid] = init_mean[tid];
  }
  __syncthreads();

  float nllp = 0.0f;

  #pragma unroll 1
  for (int t = 0; t < TQ; t++) {
    const float* zt = z_seq + ((size_t)b * TQ + t) * DQ;
    float* mRd = (t & 1) ? mv : mv2;   // m buffer read by A-merge / T-GEMV
    float* mWr = (t & 1) ? mv2 : mv;   // m buffer written by T (read by K0)

    if (t > 0) {
      const float* mu_t = mu_seq + ((size_t)b * (TQ - 1) + (t - 1)) * 4;
      const float* sg_t = sigma_seq + ((size_t)b * (TQ - 1) + (t - 1)) * 16;

      // ---- PHASE A: m-merge (one gtmp read) + build A -> Ab (bf16) ----
      if (tid < DQ) mRd[tid] += vv[tid] - r2 * gtmp[tid];
      {
        const int unit = tid >> 2, q = tid & 3;
        const int r = unit >> 1, ss = unit & 1, tt = r >> 6, i = r & 63;
        float m0 = mu_t[0], m1 = mu_t[1], m2 = mu_t[2], m3 = mu_t[3];
        float dmx, dmy, c00, c01, c11;
        if (tt == 0 && ss == 0) {
          dmx = m0; dmy = m1;
          c00 = sg_t[0]; c01 = 0.5f * (sg_t[1] + sg_t[4]); c11 = sg_t[5];
        } else if (tt == 1 && ss == 1) {
          dmx = m2; dmy = m3;
          c00 = sg_t[10]; c01 = 0.5f * (sg_t[11] + sg_t[14]); c11 = sg_t[15];
        } else {
          dmx = 0.5f * (m0 + m2); dmy = 0.5f * (m1 + m3);
          float s00 = sg_t[0];
          float s02 = 0.5f * (sg_t[2] + sg_t[8]);
          float s22 = sg_t[10];
          float s01 = 0.5f * (sg_t[1] + sg_t[4]);
          float s03 = 0.5f * (sg_t[3] + sg_t[12]);
          float s21 = 0.5f * (sg_t[9] + sg_t[6]);
          float s23 = 0.5f * (sg_t[11] + sg_t[14]);
          float s11 = sg_t[5];
          float s13 = 0.5f * (sg_t[7] + sg_t[13]);
          float s33 = sg_t[15];
          c00 = 0.25f * (s00 + s02 + s02 + s22);
          c01 = 0.25f * (s01 + s03 + s21 + s23);
          c11 = 0.25f * (s11 + s13 + s13 + s33);
        }
        float D00 = 1.0001f + 2.0f * c00;
        float D01 = 2.0f * c01;
        float D11 = 1.0001f + 2.0f * c11;
        float det = D00 * D11 - D01 * D01;
        float dinv = 1.0f / det;
        float d00 = D11 * dinv, d01 = -D01 * dinv, d11 = D00 * dinv;
        float ldts = __logf(det);
        float cix = coords[2 * i], ciy = coords[2 * i + 1];
        const float* cj = coords + q * 32;
        float kv[16];
        float rsum = 0.0f;
        #pragma unroll
        for (int u = 0; u < 16; u++) {
          float dx = cix - cj[2 * u] - dmx;
          float dy = ciy - cj[2 * u + 1] - dmy;
          float qf = d00 * dx * dx + 2.0f * d01 * dx * dy + d11 * dy * dy;
          kv[u] = __expf(-0.5f * (qf + ldts));
          rsum += kv[u];
        }
        float rtot = rsum + __shfl_xor(rsum, 1);
        rtot += __shfl_xor(rtot, 2);
        float cv = (tt == 0) ? ((ss == 0) ? cpl00 : cpl01)
                             : ((ss == 0) ? cpl10 : cpl11);
        float norm = cv / fmaxf(rtot, 1e-6f);
        #pragma unroll
        for (int u = 0; u < 16; u++) kv[u] *= norm;
        if (ss == tt && ((i >> 4) == q)) kv[i & 15] += 1.0f - damping;
        unsigned short* arow = Ab + r * LDB + ss * 64 + q * 16;
        *(uint4*)(arow) = pack8(kv);
        *(uint4*)(arow + 8) = pack8(kv + 8);
      }
      __syncthreads();

      // ---- PHASE T: mfma T = A*P + m' = A*m GEMV (single barrier) ----
      {
        f32x4 acc[4];
        #pragma unroll
        for (int c = 0; c < 4; c++) acc[c] = (f32x4){0.0f, 0.0f, 0.0f, 0.0f};
        #pragma unroll
        for (int ks = 0; ks < 4; ks++) {
          const int ko = 32 * ks + 8 * quad;
          bf16x8 a = *(const bf16x8*)(Ab + (16 * rb + m16) * LDB + ko);
          #pragma unroll
          for (int ct = 0; ct < 4; ct++) {
            bf16x8 bb = *(const bf16x8*)(Pb + (64 * ch + 16 * ct + m16) * LDB + ko);
            acc[ct] = __builtin_amdgcn_mfma_f32_16x16x32_bf16(a, bb, acc[ct], 0, 0, 0);
          }
        }
        float newm = 0.0f;
        if (tid < DQ) {
          const unsigned* ar = (const unsigned*)(Ab + tid * LDB);
          #pragma unroll 8
          for (int k2 = 0; k2 < 64; k2++) {
            unsigned p = ar[k2];
            newm = fmaf(__uint_as_float(p << 16), mRd[2 * k2], newm);
            newm = fmaf(__uint_as_float(p & 0xffff0000u), mRd[2 * k2 + 1], newm);
          }
        }
        #pragma unroll
        for (int ct = 0; ct < 4; ct++)
          #pragma unroll
          for (int reg = 0; reg < 4; reg++)
            Tb[(16 * rb + 4 * quad + reg) * LDB + 64 * ch + 16 * ct + m16] =
                f2bf(acc[ct][reg]);
        if (tid < DQ) mWr[tid] = newm;
        __syncthreads();
      }

      // ---- PHASE P': mfma Sm = T*A^T + (q2+r2) I (lower tiles) -> Wf fp32 ----
      {
        const int ctmax = rb - 4 * ch;
        f32x4 acc[4];
        #pragma unroll
        for (int c = 0; c < 4; c++) acc[c] = (f32x4){0.0f, 0.0f, 0.0f, 0.0f};
        if (ctmax >= 0) {
          #pragma unroll
          for (int ks = 0; ks < 4; ks++) {
            const int ko = 32 * ks + 8 * quad;
            bf16x8 a = *(const bf16x8*)(Tb + (16 * rb + m16) * LDB + ko);
            #pragma unroll
            for (int ct = 0; ct < 4; ct++) {
              if (ct <= ctmax) {
                bf16x8 bb = *(const bf16x8*)(Ab + (64 * ch + 16 * ct + m16) * LDB + ko);
                acc[ct] = __builtin_amdgcn_mfma_f32_16x16x32_bf16(a, bb, acc[ct], 0, 0, 0);
              }
            }
          }
        }
        __syncthreads();   // Tb reads done before fp32 Wf overwrite
        #pragma unroll
        for (int ct = 0; ct < 4; ct++) {
          if (ct <= ctmax) {
            #pragma unroll
            for (int reg = 0; reg < 4; reg++) {
              const int rg = 16 * rb + 4 * quad + reg;
              const int cgl = 64 * ch + 16 * ct + m16;
              Wf[rg * LDP + cgl] = acc[ct][reg] + ((rg == cgl) ? (q2 + r2) : 0.0f);
            }
          }
        }
        __syncthreads();
      }
    }

    // ================= measurement update =================
    // ---- PHASE K0: wave0 chol diag0 ; vv ----
    if (tid < 64) {
      chol16(Wf, mdiag, 0, lane, false);
    } else if (tid < 192) {
      const int i = tid - 64;
      vv[i] = zt[i] - mWr[i];
    }
    __syncthreads();

    // ---- chol with lookahead; wave1 inverts diag block kb concurrently ----
    #pragma unroll 1
    for (int kb = 0; kb < 7; kb++) {
      const int b0k = kb * 16, base = b0k + 16, nbelow = DQ - base;
      if (tid < nbelow) {
        const int r = base + tid;
        float* wr = Wf + r * LDP + b0k;
        float w[16];
        #pragma unroll
        for (int u4 = 0; u4 < 4; u4++) {
          float4 w4 = *(const float4*)&wr[u4 * 4];
          w[u4*4] = w4.x; w[u4*4+1] = w4.y; w[u4*4+2] = w4.z; w[u4*4+3] = w4.w;
        }
        float out[16];
        #pragma unroll
        for (int j = 0; j < 16; j++) {
          float s = w[j] * mdiag[b0k + j];
          #pragma unroll
          for (int l = 0; l < 16; l++) {
            if (l < j) s = fmaf(w[l], Wf[(b0k + l) * LDP + b0k + j], s);
          }
          out[j] = s;
        }
        #pragma unroll
        for (int u4 = 0; u4 < 4; u4++)
          *(float4*)&wr[u4 * 4] =
              make_float4(out[u4*4], out[u4*4+1], out[u4*4+2], out[u4*4+3]);
      }
      __syncthreads();
      if (tid < 64) {
        #pragma unroll
        for (int u = 0; u < 4; u++) {
          const int o = lane * 4 + u;
          const int mr = o >> 4, mc = o & 15;
          if (mr >= mc) {
            const float* pi = Wf + (base + mr) * LDP + b0k;
            const float* pj = Wf + (base + mc) * LDP + b0k;
            float s = 0.0f;
            #pragma unroll
            for (int c4 = 0; c4 < 4; c4++) {
              float4 xa = *(const float4*)&pi[c4 * 4];
              float4 yb = *(const float4*)&pj[c4 * 4];
              s = fmaf(xa.x, yb.x, s); s = fmaf(xa.y, yb.y, s);
              s = fmaf(xa.z, yb.z, s); s = fmaf(xa.w, yb.w, s);
            }
            Wf[(base + mr) * LDP + base + mc] -= s;
          }
        }
        chol16(Wf, mdiag, base, lane, kb == 6);
      } else if (tid < 80) {
        // wave1 lanes 0..15: invert diag block kb -> transposed-upper of Wf.
        const int l16 = tid - 64;      // column of Linv
        const int b0i = b0k;
        float x[16];
        #pragma unroll
        for (int i = 0; i < 16; i++) {
          const float* rip = Wf + (b0i + i) * LDP + b0i;
          float s = (i == l16) ? 1.0f : 0.0f;
          #pragma unroll
          for (int q4 = 0; q4 < 4; q4++) {
            if (q4 * 4 < i) {
              float4 lv = *(const float4*)&rip[q4 * 4];
              #pragma unroll
              for (int u = 0; u < 4; u++) {
                const int k = q4 * 4 + u;
                float lik = (u == 0) ? lv.x : (u == 1) ? lv.y
                          : (u == 2) ? lv.z : lv.w;
                if (k < i) {
                  float xk = (k >= l16) ? x[k] : 0.0f;
                  s = fmaf(-lik, xk, s);
                }
              }
            }
          }
          x[i] = s * mdiag[b0i + i];
        }
        #pragma unroll
        for (int i = 0; i < 16; i++)
          if (i > l16) Wf[(b0i + l16) * LDP + (b0i + i)] = x[i];
      } else if (tid >= 256) {
        const int grp = (tid >> 8) - 1;
        const int t8 = tid & 255;
        const int mrow = t8 >> 4, mcol = t8 & 15;
        const int mb = 7 - kb;
        int cnt = 0;
        for (int bi = 0; bi < mb; bi++) {
          for (int bj = 0; bj <= bi; bj++) {
            if (bi | bj) {
              if (cnt % 3 == grp && (bi > bj || mrow >= mcol)) {
                const int i = base + bi * 16 + mrow;
                const int j = base + bj * 16 + mcol;
                const float* pi = Wf + i * LDP + b0k;
                const float* pj = Wf + j * LDP + b0k;
                float s = 0.0f;
                #pragma unroll
                for (int c4 = 0; c4 < 4; c4++) {
                  float4 xa = *(const float4*)&pi[c4 * 4];
                  float4 yb = *(const float4*)&pj[c4 * 4];
                  s = fmaf(xa.x, yb.x, s); s = fmaf(xa.y, yb.y, s);
                  s = fmaf(xa.z, yb.z, s); s = fmaf(xa.w, yb.w, s);
                }
                Wf[i * LDP + j] -= s;
              }
              cnt++;
            }
          }
        }
      }
      __syncthreads();
    }

    // ---- trinv fused (single barrier per d): M -> transposed-upper of Wf.
    // i16 = fast lane index so G column j16 lives in 16 consecutive lanes;
    // Linv_II applied in-register via intra-wave shfl.
    #pragma unroll 1
    for (int d = 1; d < 8; d++) {
      const int z4 = tid >> 8;
      const int t8 = tid & 255;
      const int i16 = t8 & 15;
      const int j16 = t8 >> 4;
      for (int nb = z4; nb + d < 8; nb += 4) {
        const int J = nb, I = nb + d;
        const float* Lrow = Wf + (I * 16 + i16) * LDP + J * 16;
        const float* Mrow = Wf + (J * 16 + j16) * LDP + J * 16;
        const float md = mdiag[J * 16 + j16];
        float g = 0.0f;
        #pragma unroll
        for (int c4 = 0; c4 < 4; c4++) {
          float4 lv = *(const float4*)&Lrow[c4 * 4];
          float4 mq = *(const float4*)&Mrow[c4 * 4];
          float w0 = (c4*4+0 > j16) ? mq.x : ((c4*4+0 == j16) ? md : 0.0f);
          float w1 = (c4*4+1 > j16) ? mq.y : ((c4*4+1 == j16) ? md : 0.0f);
          float w2 = (c4*4+2 > j16) ? mq.z : ((c4*4+2 == j16) ? md : 0.0f);
          float w3 = (c4*4+3 > j16) ? mq.w : ((c4*4+3 == j16) ? md : 0.0f);
          g = fmaf(lv.x, w0, g); g = fmaf(lv.y, w1, g);
          g = fmaf(lv.z, w2, g); g = fmaf(lv.w, w3, g);
        }
        for (int K = J + 1; K < I; K++) {
          const float* LK = Lrow + (K - J) * 16;
          const float* MK = Wf + (J * 16 + j16) * LDP + K * 16;
          #pragma unroll
          for (int c4 = 0; c4 < 4; c4++) {
            float4 lv = *(const float4*)&LK[c4 * 4];
            float4 mq = *(const float4*)&MK[c4 * 4];
            g = fmaf(lv.x, mq.x, g); g = fmaf(lv.y, mq.y, g);
            g = fmaf(lv.z, mq.z, g); g = fmaf(lv.w, mq.w, g);
          }
        }
        // apply Linv_II: s(i16) = md_I(i16)*g(i16) + sum_{k<i16} U[k][i16] g(k)
        float s = mdiag[I * 16 + i16] * g;
        #pragma unroll
        for (int k = 0; k < 15; k++) {
          float gk = __shfl(g, (lane & 48) | k);
          if (k < i16) {
            float u = Wf[(I * 16 + k) * LDP + I * 16 + i16];
            s = fmaf(u, gk, s);
          }
        }
        Wf[(J * 16 + j16) * LDP + (I * 16 + i16)] = -s;
      }
      __syncthreads();
    }

    // ---- PHASE MC (single barrier): y=Mv + logdet; pack M^T -> Mtb (B1f) ----
    {
      const int mrow = tid >> 3, kc = (tid & 7) * 16;
      float mtv[16];
      if (kc > mrow) {
        const float4* rp = (const float4*)(Wf + mrow * LDP + kc);
        float4 q0 = rp[0], q1 = rp[1], q2v = rp[2], q3 = rp[3];
        mtv[0]=q0.x; mtv[1]=q0.y; mtv[2]=q0.z; mtv[3]=q0.w;
        mtv[4]=q1.x; mtv[5]=q1.y; mtv[6]=q1.z; mtv[7]=q1.w;
        mtv[8]=q2v.x; mtv[9]=q2v.y; mtv[10]=q2v.z; mtv[11]=q2v.w;
        mtv[12]=q3.x; mtv[13]=q3.y; mtv[14]=q3.z; mtv[15]=q3.w;
      } else if (kc + 15 < mrow) {
        #pragma unroll
        for (int u = 0; u < 16; u++) mtv[u] = 0.0f;
      } else {
        #pragma unroll
        for (int u = 0; u < 16; u++) {
          const int k = kc + u;
          mtv[u] = (k > mrow) ? Wf[mrow * LDP + k]
                 : ((k == mrow) ? mdiag[mrow] : 0.0f);
        }
      }
      if (tid < DQ) {
        nllp -= __logf(mdiag[tid]);
        float s = mdiag[tid] * vv[tid];
        for (int k = 0; k < tid; k++) s = fmaf(Wf[k * LDP + tid], vv[k], s);
        yv[tid] = s;
      }
      unsigned short* mt = Mtb + mrow * LDB + kc;
      *(uint4*)(mt) = pack8(mtv);
      *(uint4*)(mt + 8) = pack8(mtv + 8);
      __syncthreads();
    }

    // ---- PHASE Pn: mfma Sinv = M^T*M (lower); Pb = r2 I - r2^2 Sinv;
    //      Sinv*v = Mtb . yv GEMV -> gtmp (for next step's merge) ----
    {
      f32x4 acc[4];
      #pragma unroll
      for (int c = 0; c < 4; c++) acc[c] = (f32x4){0.0f, 0.0f, 0.0f, 0.0f};
      if (tid < DQ) nllp += 0.5f * yv[tid] * yv[tid];
      const int ctmax = rb - 4 * ch;
      if (ctmax >= 0) {
        for (int ks = (rb >> 1); ks < 4; ks++) {
          const int ko = 32 * ks + 8 * quad;
          bf16x8 a = *(const bf16x8*)(Mtb + (16 * rb + m16) * LDB + ko);
          #pragma unroll
          for (int ct = 0; ct < 4; ct++) {
            if (ct <= ctmax) {
              bf16x8 bb = *(const bf16x8*)(Mtb + (64 * ch + 16 * ct + m16) * LDB + ko);
              acc[ct] = __builtin_amdgcn_mfma_f32_16x16x32_bf16(a, bb, acc[ct], 0, 0, 0);
            }
          }
        }
      }
      const float nr22 = -r2 * r2;
      #pragma unroll
      for (int ct = 0; ct < 4; ct++) {
        if (ct <= ctmax) {
          const bool strict = (ct < ctmax);
          #pragma unroll
          for (int reg = 0; reg < 4; reg++) {
            const int rg = 16 * rb + 4 * quad + reg;
            const int cgl = 64 * ch + 16 * ct + m16;
            unsigned short hv = f2bf(nr22 * acc[ct][reg] + ((rg == cgl) ? r2 : 0.0f));
            Pb[rg * LDB + cgl] = hv;
            if (strict) Pb[cgl * LDB + rg] = hv;
          }
        }
      }
      if (tid < DQ) {
        const unsigned* mr = (const unsigned*)(Mtb + tid * LDB);
        float s = 0.0f;
        #pragma unroll 8
        for (int k2 = 0; k2 < 64; k2++) {
          unsigned p = mr[k2];
          s = fmaf(__uint_as_float(p << 16), yv[2 * k2], s);
          s = fmaf(__uint_as_float(p & 0xffff0000u), yv[2 * k2 + 1], s);
        }
        gtmp[tid] = s;
      }
      __syncthreads();
    }
  }

  float total = block_reduce_sum(nllp, red);
  if (tid == 0)
    nll_out[b] = total + (float)TQ * 0.5f * (float)DQ * LOG2PI;
}

extern "C" __global__ void ide_finalize(const float* __restrict__ part,
                                        float* __restrict__ out) {
  if (threadIdx.x == 0) {
    float s = 0.0f;
    for (int i = 0; i < BQ; i++) s += part[i];
    out[0] = s * (1.0f / BQ);
  }
}

extern "C" void kernel_launch(void* const* d_in, const int* in_sizes, int n_in,
                              void* d_out, int out_size, void* d_ws, size_t ws_size,
                              hipStream_t stream) {
  (void)in_sizes; (void)n_in; (void)out_size; (void)ws_size;
  const float* z_seq        = (const float*)d_in[0];
  const float* site_lon     = (const float*)d_in[1];
  const float* site_lat     = (const float*)d_in[2];
  const float* mu_seq       = (const float*)d_in[3];
  const float* sigma_seq    = (const float*)d_in[4];
  const float* log_q        = (const float*)d_in[5];
  const float* log_r        = (const float*)d_in[6];
  const float* log_p0       = (const float*)d_in[7];
  const float* log_damp     = (const float*)d_in[8];
  const float* init_mean    = (const float*)d_in[9];
  const float* coupling_raw = (const float*)d_in[10];
  float* ws = (float*)d_ws;
  float* out = (float*)d_out;

  const size_t smem_bytes = (size_t)SMEM_FLOATS * sizeof(float);
  hipFuncSetAttribute((const void*)ide_kf_kernel,
                      hipFuncAttributeMaxDynamicSharedMemorySize,
                      (int)smem_bytes);

  hipLaunchKernelGGL(ide_kf_kernel, dim3(BQ), dim3(NTH), smem_bytes, stream,
                     z_seq, site_lon, site_lat, mu_seq, sigma_seq,
                     log_q, log_r, log_p0, log_damp, init_mean, coupling_raw,
                     ws);
  hipLaunchKernelGGL(ide_finalize, dim3(1), dim3(64), 0, stream, ws, out);
}